// Round 12
// baseline (751.765 us; speedup 1.0000x reference)
//
#include <hip/hip_runtime.h>
#include <stdint.h>

// ---------------- problem constants ----------------
#define NCODES 8192
#define DIM 256
#define NROWS 65536  // 16*64*64

// d_out layout (f32 elements): z_q | codebook_loss | commitment_loss | indices
#define OUT_L0 16777216
#define OUT_L1 16777217
#define OUT_IDX 16777218

// workspace byte offsets
#define WS_IMG 0u        // u16[8192*256] f16 image of w*8192
#define WS_HV 4194304u   // float[8192]   fl32(4096*||e||^2) coarse
#define WS_C32 4227072u  // float[8192]   np-replica f32 ||e||^2
#define WS_A32 4259840u  // float[65536]  np-replica f32 ||z||^2
#define WS_TOP3 4521984u // int4[65536]   (i1,i2,i3, v1<<1|flag)
#define WS_DROW 5570560u // double[65536] per-row exact d^2 of winner
#define WS_CNT 6094848u  // int counter
#define WS_LIST 6094864u // int[65536] flagged rows
#define WS_MKEY 6357008u // u64[65536] atomicMin keys (flagged)

// flag threshold: 0.40 v-units * 512 int-units/v = 204.8 -> 205
#define TAU_INT 205u

typedef __attribute__((ext_vector_type(8))) short s8v;
typedef __attribute__((ext_vector_type(8))) _Float16 f16x8;
typedef __attribute__((ext_vector_type(4))) float f4v;
typedef unsigned short u16;
typedef unsigned long long u64;

__device__ __forceinline__ u16 f2h_bits(float x) {
  return __builtin_bit_cast(u16, (_Float16)x);
}
// monotone f32 -> u32 order map (fb keys; handles either sign)
__device__ __forceinline__ unsigned fmono(float v) {
  unsigned u = __float_as_uint(v);
  return u ^ ((unsigned)((int)u >> 31) | 0x80000000u);
}
// np f32 score: s = fl(fl(A - fl(2*Gf)) + C)  (exact IEEE f32 op sequence)
__device__ __forceinline__ float np_score(float A, float Gf, float C) {
  const float g2 = 2.0f * Gf;
  const float t = A - g2;
  return t + C;
}
// single-instruction median-of-3 (gfx9+): sorted-quad insert primitive
__device__ __forceinline__ unsigned med3u(unsigned a, unsigned b, unsigned c) {
  unsigned d;
  asm("v_med3_u32 %0, %1, %2, %3" : "=v"(d) : "v"(a), "v"(b), "v"(c));
  return d;
}

// ---------------- rowA: np-pairwise-replica f32 sum of x_d^2 per row ----------------
__global__ __launch_bounds__(256) void vq_rowA(const float* __restrict__ x,
                                               float* __restrict__ out) {
  __shared__ float sq[4][256];
  __shared__ float rb[4][16];
  const int wv = threadIdx.x >> 6, lane = threadIdx.x & 63;
  const int row = blockIdx.x * 4 + wv;
  const float4 v = *(const float4*)(x + (size_t)row * DIM + lane * 4);
  sq[wv][lane * 4 + 0] = v.x * v.x;
  sq[wv][lane * 4 + 1] = v.y * v.y;
  sq[wv][lane * 4 + 2] = v.z * v.z;
  sq[wv][lane * 4 + 3] = v.w * v.w;
  __syncthreads();
  if (lane < 16) {
    const int j = lane & 7, hb = (lane >> 3) * 128;
    float r = sq[wv][hb + j];
    for (int i = 1; i < 16; ++i) r += sq[wv][hb + i * 8 + j];  // sequential, ascending
    rb[wv][lane] = r;
  }
  __syncthreads();
  if (lane == 0) {
    const float* r = rb[wv];
    const float h0 = ((r[0] + r[1]) + (r[2] + r[3])) + ((r[4] + r[5]) + (r[6] + r[7]));
    const float h1 = ((r[8] + r[9]) + (r[10] + r[11])) + ((r[12] + r[13]) + (r[14] + r[15]));
    out[row] = h0 + h1;
  }
}

// ---------------- prep: f16 image (x8192) + coarse hv + cnt=0 ----------------
__global__ __launch_bounds__(256) void vq_prep(const float* __restrict__ w,
                                               u16* __restrict__ img,
                                               float* __restrict__ hv,
                                               int* __restrict__ cnt) {
  if (blockIdx.x == 0 && threadIdx.x == 0) *cnt = 0;
  const int wv = threadIdx.x >> 6, lane = threadIdx.x & 63;
  const int code = blockIdx.x * 4 + wv;
  const float4 v = *(const float4*)(w + (size_t)code * DIM + lane * 4);
  ushort4 us;
  us.x = f2h_bits(v.x * 8192.0f);
  us.y = f2h_bits(v.y * 8192.0f);
  us.z = f2h_bits(v.z * 8192.0f);
  us.w = f2h_bits(v.w * 8192.0f);
  *(ushort4*)(img + (size_t)code * DIM + lane * 4) = us;
  double s = 0.0;
  s = fma((double)v.x, (double)v.x, s);
  s = fma((double)v.y, (double)v.y, s);
  s = fma((double)v.z, (double)v.z, s);
  s = fma((double)v.w, (double)v.w, s);
#pragma unroll
  for (int m = 1; m <= 32; m <<= 1) s += __shfl_xor(s, m, 64);
  if (lane == 0) hv[code] = (float)(4096.0 * s);
}

// merge two ascending sorted 4-tuples -> smallest 4 of union
#define MERGE4(a1, a2, a3, a4, b1, b2, b3, b4)                          \
  {                                                                     \
    const unsigned x11 = max(a1, b1);                                   \
    const unsigned o1 = min(a1, b1);                                    \
    const unsigned o2 = min(min(a2, b2), x11);                          \
    const unsigned x21 = max(a2, b1), x12 = max(a1, b2);                \
    const unsigned o3 = min(min(a3, b3), min(x21, x12));                \
    const unsigned x31 = max(a3, b1), x22 = max(a2, b2), x13 = max(a1, b3); \
    const unsigned o4 = min(min(a4, b4), min(min(x31, x22), x13));      \
    a1 = o1; a2 = o2; a3 = o3; a4 = o4;                                 \
  }

// ---------------- main: LDS-staged f16 MFMA + per-row top-4 int keys + flag ----------------
// (unchanged from round 11 except top3.w now carries (v1i<<1)|flag)
__global__ __launch_bounds__(256, 3) void vq_main(const float* __restrict__ z,
                                                  const u16* __restrict__ img,
                                                  const float* __restrict__ hv,
                                                  int4* __restrict__ top3,
                                                  int* __restrict__ cnt,
                                                  int* __restrict__ list,
                                                  u64* __restrict__ mkey) {
  __shared__ __align__(16) char lds[2][16384];
  const int tid = threadIdx.x, wv = tid >> 6, lane = tid & 63;
  const int ll = lane & 15, lh = lane >> 4;
  const int myrow = blockIdx.x * 128 + wv * 32;  // wave's 32 rows

  // A fragments: lane holds z[myrow+rt*16+ll][c*32 + lh*8 + j] as f16 (64 VGPR)
  f16x8 A[2][8];
#pragma unroll
  for (int rt = 0; rt < 2; ++rt) {
    const float* zr = z + (size_t)(myrow + rt * 16 + ll) * DIM;
#pragma unroll
    for (int c = 0; c < 8; ++c) {
      const float4 a = *(const float4*)(zr + c * 32 + lh * 8);
      const float4 b = *(const float4*)(zr + c * 32 + lh * 8 + 4);
      f16x8 t;
      t[0] = (_Float16)a.x; t[1] = (_Float16)a.y;
      t[2] = (_Float16)a.z; t[3] = (_Float16)a.w;
      t[4] = (_Float16)b.x; t[5] = (_Float16)b.y;
      t[6] = (_Float16)b.z; t[7] = (_Float16)b.w;
      A[rt][c] = t;
    }
  }

  // per-slot (s = rt*4+j) ascending top-4 keys (32 VGPR)
  unsigned k1[8], k2[8], k3[8], k4[8];
#pragma unroll
  for (int s = 0; s < 8; ++s) {
    k1[s] = 0xFFFFFFFFu; k2[s] = 0xFFFFFFFFu;
    k3[s] = 0xFFFFFFFFu; k4[s] = 0xFFFFFFFFu;
  }

  // transposed staging source offsets: dest o = (p*4+wv)*1024 + lane*16 (linear),
  // src = code*512 + g*16 with code = lane&31, g = (p*4+wv)*2 + (lane>>5)
  unsigned soff[4];
#pragma unroll
  for (int p = 0; p < 4; ++p)
    soff[p] = (unsigned)((lane & 31) * 512 + ((p * 4 + wv) * 2 + (lane >> 5)) * 16);

  auto STAGE = [&](int t, int buf) {
    const char* src = (const char*)img + (size_t)t * 16384;
#pragma unroll
    for (int p = 0; p < 4; ++p) {
      __builtin_amdgcn_global_load_lds(
          (const __attribute__((address_space(1))) unsigned int*)(src + soff[p]),
          (__attribute__((address_space(3))) unsigned int*)(&lds[buf][(p * 4 + wv) * 1024]),
          16, 0, 0);
    }
  };

  // per-lane ds_read base: lh*512 + ll*16; c,ct offsets are immediates
  const int rbase = lh * 512 + ll * 16;

  STAGE(0, 0);
  __syncthreads();
#pragma unroll 1
  for (int t = 0; t < 256; ++t) {
    const int buf = t & 1;
    if (t + 1 < 256) STAGE(t + 1, buf ^ 1);  // prefetch flies under compute

    const float hb0 = fmaf(hv[t * 32 + ll], 512.0f, 262144.0f);       // (hv+512)*512
    const float hb1 = fmaf(hv[t * 32 + 16 + ll], 512.0f, 262144.0f);
    const char* bp = &lds[buf][rbase];

    f4v a00 = (f4v){0.f, 0.f, 0.f, 0.f}, a01 = (f4v){0.f, 0.f, 0.f, 0.f};
    f4v a10 = (f4v){0.f, 0.f, 0.f, 0.f}, a11 = (f4v){0.f, 0.f, 0.f, 0.f};
#pragma unroll
    for (int c = 0; c < 8; ++c) {
      const f16x8 b0 = *(const f16x8*)(bp + c * 2048);        // ct=0
      const f16x8 b1 = *(const f16x8*)(bp + c * 2048 + 256);  // ct=1
      a00 = __builtin_amdgcn_mfma_f32_16x16x32_f16(A[0][c], b0, a00, 0, 0, 0);
      a01 = __builtin_amdgcn_mfma_f32_16x16x32_f16(A[0][c], b1, a01, 0, 0, 0);
      a10 = __builtin_amdgcn_mfma_f32_16x16x32_f16(A[1][c], b0, a10, 0, 0, 0);
      a11 = __builtin_amdgcn_mfma_f32_16x16x32_f16(A[1][c], b1, a11, 0, 0, 0);
    }

    const unsigned iv0 = (unsigned)(t * 32 + ll);
    const unsigned iv1 = iv0 + 16u;
#pragma unroll
    for (int rt = 0; rt < 2; ++rt) {
      const f4v& c0 = rt ? a10 : a00;
      const f4v& c1 = rt ? a11 : a01;
#pragma unroll
      for (int j = 0; j < 4; ++j) {
        const int s = rt * 4 + j;
        const float u0 = fmaf(c0[j], -512.0f, hb0);
        const unsigned key0 = (((unsigned)u0) << 13) | iv0;
        const unsigned n1 = min(k1[s], key0);
        const unsigned n2 = med3u(k1[s], key0, k2[s]);
        const unsigned n3 = med3u(k2[s], key0, k3[s]);
        const unsigned n4 = med3u(k3[s], key0, k4[s]);
        const float u1 = fmaf(c1[j], -512.0f, hb1);
        const unsigned key1 = (((unsigned)u1) << 13) | iv1;
        k1[s] = min(n1, key1);
        k2[s] = med3u(n1, key1, n2);
        k3[s] = med3u(n2, key1, n3);
        k4[s] = med3u(n3, key1, n4);
      }
    }
    __syncthreads();  // drains prefetch vmcnt + all waves done with buf
  }

  // ---- merge across the 16 column-lanes (butterfly); wave owns its 32 rows ----
#pragma unroll
  for (int rt = 0; rt < 2; ++rt)
#pragma unroll
    for (int j = 0; j < 4; ++j) {
      const int s = rt * 4 + j;
      unsigned a1 = k1[s], a2 = k2[s], a3 = k3[s], a4 = k4[s];
#pragma unroll
      for (int m = 1; m <= 8; m <<= 1) {
        unsigned b1 = (unsigned)__shfl_xor((int)a1, m, 64);
        unsigned b2 = (unsigned)__shfl_xor((int)a2, m, 64);
        unsigned b3 = (unsigned)__shfl_xor((int)a3, m, 64);
        unsigned b4 = (unsigned)__shfl_xor((int)a4, m, 64);
        MERGE4(a1, a2, a3, a4, b1, b2, b3, b4);
      }
      if (ll == 0) {  // C/D: col=lane&15, row=(lane>>4)*4+j
        const int row = myrow + rt * 16 + lh * 4 + j;
        const int flag = ((a4 >> 13) - (a1 >> 13)) < TAU_INT ? 1 : 0;
        // .w carries coarse v1 int key (19b) << 1 | flag -> fb filter threshold
        top3[row] = make_int4((int)(a1 & 0x1FFFu), (int)(a2 & 0x1FFFu), (int)(a3 & 0x1FFFu),
                              (int)(((a1 >> 13) << 1) | (unsigned)flag));
        if (flag) {
          mkey[row] = ~0ull;
          list[atomicAdd(cnt, 1)] = row;
        }
      }
    }
}

// ---------------- refine (unflagged): np-replica s over top-3, first-index tie ----------------
__global__ __launch_bounds__(256) void vq_refine(const float* __restrict__ z,
                                                 const float* __restrict__ w,
                                                 const float* __restrict__ A32,
                                                 const float* __restrict__ C32,
                                                 const int4* __restrict__ top3,
                                                 float* __restrict__ out,
                                                 double* __restrict__ drow) {
  const int wv = threadIdx.x >> 6, lane = threadIdx.x & 63;
  const int row = blockIdx.x * 4 + wv;
  const int4 cc = top3[row];
  if (cc.w & 1) return;  // flagged -> fallback path owns this row
  const float4 zv = *(const float4*)(z + (size_t)row * DIM + lane * 4);
  const double z0 = (double)zv.x, z1 = (double)zv.y, z2 = (double)zv.z, z3 = (double)zv.w;
  const int cand[3] = {cc.x, cc.y, cc.z};
  float4 ev[3];
  float sc[3];
  const float A = A32[row];
#pragma unroll
  for (int k = 0; k < 3; ++k) {
    ev[k] = *(const float4*)(w + (size_t)cand[k] * DIM + lane * 4);
    double d = 0.0;
    d = fma(z0, (double)ev[k].x, d);
    d = fma(z1, (double)ev[k].y, d);
    d = fma(z2, (double)ev[k].z, d);
    d = fma(z3, (double)ev[k].w, d);
#pragma unroll
    for (int m = 1; m <= 32; m <<= 1) d += __shfl_xor(d, m, 64);
    sc[k] = np_score(A, (float)d, C32[cand[k]]);
  }
  // np.argmin: min value, first (lowest) index on exact tie
  int win = cand[0], wk = 0;
  float sw = sc[0];
#pragma unroll
  for (int k = 1; k < 3; ++k) {
    const bool take = (sc[k] < sw) || (sc[k] == sw && cand[k] < win);
    sw = take ? sc[k] : sw;
    win = take ? cand[k] : win;
    wk = take ? k : wk;
  }
  const float4 q = ev[wk];
  *(float4*)(out + (size_t)row * DIM + lane * 4) = q;
  double dd = 0.0, tt;
  tt = (double)zv.x - (double)q.x; dd = fma(tt, tt, dd);
  tt = (double)zv.y - (double)q.y; dd = fma(tt, tt, dd);
  tt = (double)zv.z - (double)q.z; dd = fma(tt, tt, dd);
  tt = (double)zv.w - (double)q.w; dd = fma(tt, tt, dd);
#pragma unroll
  for (int m = 1; m <= 32; m <<= 1) dd += __shfl_xor(dd, m, 64);
  if (lane == 0) {
    out[OUT_IDX + row] = (float)win;
    drow[row] = dd;
  }
}

// ---------------- fallback scan (flagged): f32 filter + f64 confirm ----------------
// grid 2048 = 256 code-slices x 8 row-groups; block 256 = 8 rows x 32 codes.
// f32 dual-acc dot (err <= ~6e-7) filters; np-winner provably satisfies
// s_pre <= A + (v1hi + 0.6)/4096 (f16-coarse err + key-trunc + np-round + filter err),
// threshold uses +1.2 (2x margin). Only ~6-10 codes/row take the f64 path.
__global__ __launch_bounds__(256) void vq_fb_scan(const float* __restrict__ z,
                                                  const float* __restrict__ w,
                                                  const float* __restrict__ A32,
                                                  const float* __restrict__ C32,
                                                  const int4* __restrict__ top3,
                                                  const int* __restrict__ cnt,
                                                  const int* __restrict__ list,
                                                  u64* __restrict__ mkey) {
  const int slice = blockIdx.x >> 3, rg = blockIdx.x & 7;
  const int cl = threadIdx.x & 31;  // code lane within slice
  const int code = slice * 32 + cl;
  const int rslot = threadIdx.x >> 5;
  const int n = *cnt;
  const float* wr = w + (size_t)code * DIM;
  const float Cc = C32[code];
  for (int r0 = rg * 8; r0 < n; r0 += 64) {
    const int r = r0 + rslot;  // uniform within the 32-lane group
    if (r >= n) continue;
    const int row = list[r];
    const int4 t3 = top3[row];
    const float A = A32[row];
    // v1hi = upper bound on coarse v1: (v1i+1)/512 - 512
    const float v1hi = (float)((((unsigned)t3.w) >> 1) + 1u) * (1.0f / 512.0f) - 512.0f;
    const float thr = A + (v1hi + 1.2f) * (1.0f / 4096.0f);
    const float* zr = z + (size_t)row * DIM;
    float a0 = 0.f, a1 = 0.f, a2 = 0.f, a3 = 0.f;
#pragma unroll 4
    for (int d = 0; d < DIM; d += 4) {
      const float4 zq = *(const float4*)(zr + d);
      const float4 wq = *(const float4*)(wr + d);
      a0 = fmaf(zq.x, wq.x, a0);
      a1 = fmaf(zq.y, wq.y, a1);
      a2 = fmaf(zq.z, wq.z, a2);
      a3 = fmaf(zq.w, wq.w, a3);
    }
    const float s_pre = np_score(A, (a0 + a1) + (a2 + a3), Cc);
    if (s_pre <= thr || code == t3.x) {  // t3.x: guaranteed >=1 writer per row
      double g0 = 0.0, g1 = 0.0;  // dual accumulators: break f64 fma chain
#pragma unroll 4
      for (int d = 0; d < DIM; d += 4) {
        const float4 zq = *(const float4*)(zr + d);
        const float4 wq = *(const float4*)(wr + d);
        g0 = fma((double)zq.x, (double)wq.x, g0);
        g1 = fma((double)zq.y, (double)wq.y, g1);
        g0 = fma((double)zq.z, (double)wq.z, g0);
        g1 = fma((double)zq.w, (double)wq.w, g1);
      }
      const float s = np_score(A, (float)(g0 + g1), Cc);
      atomicMin(&mkey[row], ((u64)fmono(s) << 13) | (u64)code);
    }
  }
}

// ---------------- fallback write: winner -> z_q, idx, drow ----------------
__global__ __launch_bounds__(256) void vq_fb_write(const float* __restrict__ z,
                                                   const float* __restrict__ w,
                                                   const int* __restrict__ cnt,
                                                   const int* __restrict__ list,
                                                   const u64* __restrict__ mkey,
                                                   float* __restrict__ out,
                                                   double* __restrict__ drow) {
  const int wv = threadIdx.x >> 6, lane = threadIdx.x & 63;
  const int n = *cnt;
  for (int k = blockIdx.x * 4 + wv; k < n; k += 1024) {
    const int row = list[k];
    const int win = (int)(mkey[row] & 0x1FFFull);
    const float4 zv = *(const float4*)(z + (size_t)row * DIM + lane * 4);
    const float4 q = *(const float4*)(w + (size_t)win * DIM + lane * 4);
    *(float4*)(out + (size_t)row * DIM + lane * 4) = q;
    double dd = 0.0, tt;
    tt = (double)zv.x - (double)q.x; dd = fma(tt, tt, dd);
    tt = (double)zv.y - (double)q.y; dd = fma(tt, tt, dd);
    tt = (double)zv.z - (double)q.z; dd = fma(tt, tt, dd);
    tt = (double)zv.w - (double)q.w; dd = fma(tt, tt, dd);
#pragma unroll
    for (int m = 1; m <= 32; m <<= 1) dd += __shfl_xor(dd, m, 64);
    if (lane == 0) {
      out[OUT_IDX + row] = (float)win;
      drow[row] = dd;
    }
  }
}

// ---------------- loss: deterministic f64 reduction ----------------
__global__ __launch_bounds__(256) void vq_loss(const double* __restrict__ drow,
                                               float* __restrict__ out) {
  __shared__ double sd[256];
  double s = 0.0;
  for (int i = threadIdx.x; i < NROWS; i += 256) s += drow[i];
  sd[threadIdx.x] = s;
  __syncthreads();
  if (threadIdx.x == 0) {
    double tot = 0.0;
    for (int i = 0; i < 256; ++i) tot += sd[i];
    const float loss = (float)(tot / 16777216.0);
    out[OUT_L0] = loss;
    out[OUT_L1] = loss;
  }
}

extern "C" void kernel_launch(void* const* d_in, const int* in_sizes, int n_in,
                              void* d_out, int out_size, void* d_ws, size_t ws_size,
                              hipStream_t stream) {
  const float* z = (const float*)d_in[0];  // f32 [65536, 256]
  const float* w = (const float*)d_in[1];  // f32 [8192, 256]
  float* out = (float*)d_out;
  unsigned char* ws = (unsigned char*)d_ws;
  u16* img = (u16*)(ws + WS_IMG);
  float* hv = (float*)(ws + WS_HV);
  float* C32 = (float*)(ws + WS_C32);
  float* A32 = (float*)(ws + WS_A32);
  int4* top3 = (int4*)(ws + WS_TOP3);
  double* drow = (double*)(ws + WS_DROW);
  int* cnt = (int*)(ws + WS_CNT);
  int* list = (int*)(ws + WS_LIST);
  u64* mkey = (u64*)(ws + WS_MKEY);

  vq_prep<<<NCODES / 4, 256, 0, stream>>>(w, img, hv, cnt);
  vq_rowA<<<NCODES / 4, 256, 0, stream>>>(w, C32);   // np-replica ||e||^2
  vq_rowA<<<NROWS / 4, 256, 0, stream>>>(z, A32);    // np-replica ||z||^2
  vq_main<<<NROWS / 128, 256, 0, stream>>>(z, img, hv, top3, cnt, list, mkey);
  vq_refine<<<NROWS / 4, 256, 0, stream>>>(z, w, A32, C32, top3, out, drow);
  vq_fb_scan<<<2048, 256, 0, stream>>>(z, w, A32, C32, top3, cnt, list, mkey);
  vq_fb_write<<<256, 256, 0, stream>>>(z, w, cnt, list, mkey, out, drow);
  vq_loss<<<1, 256, 0, stream>>>(drow, out);
}

// Round 13
// 703.120 us; speedup vs baseline: 1.0692x; 1.0692x over previous
//
#include <hip/hip_runtime.h>
#include <stdint.h>

// ---------------- problem constants ----------------
#define NCODES 8192
#define DIM 256
#define NROWS 65536  // 16*64*64

// d_out layout (f32 elements): z_q | codebook_loss | commitment_loss | indices
#define OUT_L0 16777216
#define OUT_L1 16777217
#define OUT_IDX 16777218

// workspace byte offsets
#define WS_IMG 0u        // u16[8192*256] f16 image of w*8192
#define WS_HV 4194304u   // float[8192]   fl32(4096*||e||^2) coarse
#define WS_C32 4227072u  // float[8192]   np-replica f32 ||e||^2
#define WS_A32 4259840u  // float[65536]  np-replica f32 ||z||^2
#define WS_T6A 4521984u  // int4[65536]   (i1,i2,i3, v1<<1|flag)
#define WS_T6B 5570560u  // int4[65536]   (i4,i5,i6, 0)
#define WS_DROW 6619136u // double[65536] per-row exact d^2 of winner
#define WS_CNT 7143424u  // int counter
#define WS_LIST 7143440u // int[65536] flagged rows
#define WS_MKEY 7399696u // u64[65536] atomicMin keys (flagged)

// flag threshold: 0.40 v-units * 512 int-units/v = 204.8 -> 205
#define TAU_INT 205u

typedef __attribute__((ext_vector_type(8))) short s8v;
typedef __attribute__((ext_vector_type(8))) _Float16 f16x8;
typedef __attribute__((ext_vector_type(4))) float f4v;
typedef unsigned short u16;
typedef unsigned long long u64;

__device__ __forceinline__ u16 f2h_bits(float x) {
  return __builtin_bit_cast(u16, (_Float16)x);
}
// monotone f32 -> u32 order map (fb keys; handles either sign)
__device__ __forceinline__ unsigned fmono(float v) {
  unsigned u = __float_as_uint(v);
  return u ^ ((unsigned)((int)u >> 31) | 0x80000000u);
}
// np f32 score: s = fl(fl(A - fl(2*Gf)) + C)  (exact IEEE f32 op sequence)
__device__ __forceinline__ float np_score(float A, float Gf, float C) {
  const float g2 = 2.0f * Gf;
  const float t = A - g2;
  return t + C;
}
// single-instruction median-of-3 (gfx9+): sorted-list insert primitive
__device__ __forceinline__ unsigned med3u(unsigned a, unsigned b, unsigned c) {
  unsigned d;
  asm("v_med3_u32 %0, %1, %2, %3" : "=v"(d) : "v"(a), "v"(b), "v"(c));
  return d;
}

// ---------------- rowA: np-pairwise-replica f32 sum of x_d^2 per row ----------------
__global__ __launch_bounds__(256) void vq_rowA(const float* __restrict__ x,
                                               float* __restrict__ out) {
  __shared__ float sq[4][256];
  __shared__ float rb[4][16];
  const int wv = threadIdx.x >> 6, lane = threadIdx.x & 63;
  const int row = blockIdx.x * 4 + wv;
  const float4 v = *(const float4*)(x + (size_t)row * DIM + lane * 4);
  sq[wv][lane * 4 + 0] = v.x * v.x;
  sq[wv][lane * 4 + 1] = v.y * v.y;
  sq[wv][lane * 4 + 2] = v.z * v.z;
  sq[wv][lane * 4 + 3] = v.w * v.w;
  __syncthreads();
  if (lane < 16) {
    const int j = lane & 7, hb = (lane >> 3) * 128;
    float r = sq[wv][hb + j];
    for (int i = 1; i < 16; ++i) r += sq[wv][hb + i * 8 + j];  // sequential, ascending
    rb[wv][lane] = r;
  }
  __syncthreads();
  if (lane == 0) {
    const float* r = rb[wv];
    const float h0 = ((r[0] + r[1]) + (r[2] + r[3])) + ((r[4] + r[5]) + (r[6] + r[7]));
    const float h1 = ((r[8] + r[9]) + (r[10] + r[11])) + ((r[12] + r[13]) + (r[14] + r[15]));
    out[row] = h0 + h1;
  }
}

// ---------------- prep: f16 image (x8192) + coarse hv + cnt=0 ----------------
__global__ __launch_bounds__(256) void vq_prep(const float* __restrict__ w,
                                               u16* __restrict__ img,
                                               float* __restrict__ hv,
                                               int* __restrict__ cnt) {
  if (blockIdx.x == 0 && threadIdx.x == 0) *cnt = 0;
  const int wv = threadIdx.x >> 6, lane = threadIdx.x & 63;
  const int code = blockIdx.x * 4 + wv;
  const float4 v = *(const float4*)(w + (size_t)code * DIM + lane * 4);
  ushort4 us;
  us.x = f2h_bits(v.x * 8192.0f);
  us.y = f2h_bits(v.y * 8192.0f);
  us.z = f2h_bits(v.z * 8192.0f);
  us.w = f2h_bits(v.w * 8192.0f);
  *(ushort4*)(img + (size_t)code * DIM + lane * 4) = us;
  double s = 0.0;
  s = fma((double)v.x, (double)v.x, s);
  s = fma((double)v.y, (double)v.y, s);
  s = fma((double)v.z, (double)v.z, s);
  s = fma((double)v.w, (double)v.w, s);
#pragma unroll
  for (int m = 1; m <= 32; m <<= 1) s += __shfl_xor(s, m, 64);
  if (lane == 0) hv[code] = (float)(4096.0 * s);
}

// merge two ascending sorted 6-tuples -> smallest 6 of union
// o_k = min over i+j=k of max(a_i, b_j)  (a_0/b_0 = -inf)
#define MERGE6(a1, a2, a3, a4, a5, a6, b1, b2, b3, b4, b5, b6)              \
  {                                                                         \
    const unsigned o1 = min(a1, b1);                                        \
    const unsigned o2 = min(min(a2, b2), max(a1, b1));                      \
    const unsigned o3 = min(min(a3, b3), min(max(a1, b2), max(a2, b1)));    \
    const unsigned o4 =                                                     \
        min(min(a4, b4), min(max(a1, b3), min(max(a2, b2), max(a3, b1))));  \
    const unsigned o5 = min(min(a5, b5), min(min(max(a1, b4), max(a2, b3)), \
                                             min(max(a3, b2), max(a4, b1)))); \
    const unsigned o6 =                                                     \
        min(min(a6, b6), min(min(max(a1, b5), max(a2, b4)),                 \
                             min(max(a3, b3), min(max(a4, b2), max(a5, b1))))); \
    a1 = o1; a2 = o2; a3 = o3; a4 = o4; a5 = o5; a6 = o6;                   \
  }

// ---------------- main: LDS-staged f16 MFMA + per-row top-6 int keys + flag ----------------
// grid 512 x 256 (4 waves). Block owns 128 rows; wave wv owns rows [base+wv*32, +32).
// B staged per 32-code tile (16KB) into 2x16KB LDS dbuf via global_load_lds with
// TRANSPOSED source (r11, 0 bank conflicts). key = (u<<13)|code, u = trunc(512*(v+512)).
// Top-6 keys => flag = (v6-v1 < TAU) certifies np-winner in {i1..i6}; expected
// flagged rows ~5-50 (Poisson mu=0.45 fit from r6's 8.5% top-3 flag rate).
__global__ __launch_bounds__(256, 3) void vq_main(const float* __restrict__ z,
                                                  const u16* __restrict__ img,
                                                  const float* __restrict__ hv,
                                                  int4* __restrict__ t6a,
                                                  int4* __restrict__ t6b,
                                                  int* __restrict__ cnt,
                                                  int* __restrict__ list,
                                                  u64* __restrict__ mkey) {
  __shared__ __align__(16) char lds[2][16384];
  const int tid = threadIdx.x, wv = tid >> 6, lane = tid & 63;
  const int ll = lane & 15, lh = lane >> 4;
  const int myrow = blockIdx.x * 128 + wv * 32;  // wave's 32 rows

  // A fragments: lane holds z[myrow+rt*16+ll][c*32 + lh*8 + j] as f16 (64 VGPR)
  f16x8 A[2][8];
#pragma unroll
  for (int rt = 0; rt < 2; ++rt) {
    const float* zr = z + (size_t)(myrow + rt * 16 + ll) * DIM;
#pragma unroll
    for (int c = 0; c < 8; ++c) {
      const float4 a = *(const float4*)(zr + c * 32 + lh * 8);
      const float4 b = *(const float4*)(zr + c * 32 + lh * 8 + 4);
      f16x8 t;
      t[0] = (_Float16)a.x; t[1] = (_Float16)a.y;
      t[2] = (_Float16)a.z; t[3] = (_Float16)a.w;
      t[4] = (_Float16)b.x; t[5] = (_Float16)b.y;
      t[6] = (_Float16)b.z; t[7] = (_Float16)b.w;
      A[rt][c] = t;
    }
  }

  // per-slot (s = rt*4+j) ascending top-6 keys (48 VGPR)
  unsigned k1[8], k2[8], k3[8], k4[8], k5[8], k6[8];
#pragma unroll
  for (int s = 0; s < 8; ++s) {
    k1[s] = 0xFFFFFFFFu; k2[s] = 0xFFFFFFFFu; k3[s] = 0xFFFFFFFFu;
    k4[s] = 0xFFFFFFFFu; k5[s] = 0xFFFFFFFFu; k6[s] = 0xFFFFFFFFu;
  }

  // transposed staging source offsets (r11): dest linear, src = code*512 + g*16
  unsigned soff[4];
#pragma unroll
  for (int p = 0; p < 4; ++p)
    soff[p] = (unsigned)((lane & 31) * 512 + ((p * 4 + wv) * 2 + (lane >> 5)) * 16);

  auto STAGE = [&](int t, int buf) {
    const char* src = (const char*)img + (size_t)t * 16384;
#pragma unroll
    for (int p = 0; p < 4; ++p) {
      __builtin_amdgcn_global_load_lds(
          (const __attribute__((address_space(1))) unsigned int*)(src + soff[p]),
          (__attribute__((address_space(3))) unsigned int*)(&lds[buf][(p * 4 + wv) * 1024]),
          16, 0, 0);
    }
  };

  // per-lane ds_read base: lh*512 + ll*16; c,ct offsets are immediates
  const int rbase = lh * 512 + ll * 16;

  STAGE(0, 0);
  __syncthreads();
#pragma unroll 1
  for (int t = 0; t < 256; ++t) {
    const int buf = t & 1;
    if (t + 1 < 256) STAGE(t + 1, buf ^ 1);  // prefetch flies under compute

    const float hb0 = fmaf(hv[t * 32 + ll], 512.0f, 262144.0f);       // (hv+512)*512
    const float hb1 = fmaf(hv[t * 32 + 16 + ll], 512.0f, 262144.0f);
    const char* bp = &lds[buf][rbase];

    f4v a00 = (f4v){0.f, 0.f, 0.f, 0.f}, a01 = (f4v){0.f, 0.f, 0.f, 0.f};
    f4v a10 = (f4v){0.f, 0.f, 0.f, 0.f}, a11 = (f4v){0.f, 0.f, 0.f, 0.f};
#pragma unroll
    for (int c = 0; c < 8; ++c) {
      const f16x8 b0 = *(const f16x8*)(bp + c * 2048);        // ct=0
      const f16x8 b1 = *(const f16x8*)(bp + c * 2048 + 256);  // ct=1
      a00 = __builtin_amdgcn_mfma_f32_16x16x32_f16(A[0][c], b0, a00, 0, 0, 0);
      a01 = __builtin_amdgcn_mfma_f32_16x16x32_f16(A[0][c], b1, a01, 0, 0, 0);
      a10 = __builtin_amdgcn_mfma_f32_16x16x32_f16(A[1][c], b0, a10, 0, 0, 0);
      a11 = __builtin_amdgcn_mfma_f32_16x16x32_f16(A[1][c], b1, a11, 0, 0, 0);
    }

    const unsigned iv0 = (unsigned)(t * 32 + ll);
    const unsigned iv1 = iv0 + 16u;
#pragma unroll
    for (int rt = 0; rt < 2; ++rt) {
      const f4v& c0 = rt ? a10 : a00;
      const f4v& c1 = rt ? a11 : a01;
#pragma unroll
      for (int j = 0; j < 4; ++j) {
        const int s = rt * 4 + j;
        const float u0 = fmaf(c0[j], -512.0f, hb0);
        const unsigned key0 = (((unsigned)u0) << 13) | iv0;
        const unsigned n1 = min(k1[s], key0);
        const unsigned n2 = med3u(k1[s], key0, k2[s]);
        const unsigned n3 = med3u(k2[s], key0, k3[s]);
        const unsigned n4 = med3u(k3[s], key0, k4[s]);
        const unsigned n5 = med3u(k4[s], key0, k5[s]);
        const unsigned n6 = med3u(k5[s], key0, k6[s]);
        const float u1 = fmaf(c1[j], -512.0f, hb1);
        const unsigned key1 = (((unsigned)u1) << 13) | iv1;
        k1[s] = min(n1, key1);
        k2[s] = med3u(n1, key1, n2);
        k3[s] = med3u(n2, key1, n3);
        k4[s] = med3u(n3, key1, n4);
        k5[s] = med3u(n4, key1, n5);
        k6[s] = med3u(n5, key1, n6);
      }
    }
    __syncthreads();  // drains prefetch vmcnt + all waves done with buf
  }

  // ---- merge across the 16 column-lanes (butterfly); wave owns its 32 rows ----
#pragma unroll
  for (int rt = 0; rt < 2; ++rt)
#pragma unroll
    for (int j = 0; j < 4; ++j) {
      const int s = rt * 4 + j;
      unsigned a1 = k1[s], a2 = k2[s], a3 = k3[s], a4 = k4[s], a5 = k5[s], a6 = k6[s];
#pragma unroll
      for (int m = 1; m <= 8; m <<= 1) {
        unsigned b1 = (unsigned)__shfl_xor((int)a1, m, 64);
        unsigned b2 = (unsigned)__shfl_xor((int)a2, m, 64);
        unsigned b3 = (unsigned)__shfl_xor((int)a3, m, 64);
        unsigned b4 = (unsigned)__shfl_xor((int)a4, m, 64);
        unsigned b5 = (unsigned)__shfl_xor((int)a5, m, 64);
        unsigned b6 = (unsigned)__shfl_xor((int)a6, m, 64);
        MERGE6(a1, a2, a3, a4, a5, a6, b1, b2, b3, b4, b5, b6);
      }
      if (ll == 0) {  // C/D: col=lane&15, row=(lane>>4)*4+j
        const int row = myrow + rt * 16 + lh * 4 + j;
        const int flag = ((a6 >> 13) - (a1 >> 13)) < TAU_INT ? 1 : 0;
        t6a[row] = make_int4((int)(a1 & 0x1FFFu), (int)(a2 & 0x1FFFu), (int)(a3 & 0x1FFFu),
                             (int)(((a1 >> 13) << 1) | (unsigned)flag));
        t6b[row] = make_int4((int)(a4 & 0x1FFFu), (int)(a5 & 0x1FFFu), (int)(a6 & 0x1FFFu), 0);
        if (flag) {
          mkey[row] = ~0ull;
          list[atomicAdd(cnt, 1)] = row;
        }
      }
    }
}

// ---------------- refine (unflagged): np-replica s over top-6, first-index tie ----------------
__global__ __launch_bounds__(256) void vq_refine(const float* __restrict__ z,
                                                 const float* __restrict__ w,
                                                 const float* __restrict__ A32,
                                                 const float* __restrict__ C32,
                                                 const int4* __restrict__ t6a,
                                                 const int4* __restrict__ t6b,
                                                 float* __restrict__ out,
                                                 double* __restrict__ drow) {
  const int wv = threadIdx.x >> 6, lane = threadIdx.x & 63;
  const int row = blockIdx.x * 4 + wv;
  const int4 ca = t6a[row];
  if (ca.w & 1) return;  // flagged -> fallback path owns this row
  const int4 cb = t6b[row];
  const float4 zv = *(const float4*)(z + (size_t)row * DIM + lane * 4);
  const double z0 = (double)zv.x, z1 = (double)zv.y, z2 = (double)zv.z, z3 = (double)zv.w;
  const int cand[6] = {ca.x, ca.y, ca.z, cb.x, cb.y, cb.z};
  float4 ev[6];
  float sc[6];
  const float A = A32[row];
#pragma unroll
  for (int k = 0; k < 6; ++k) {
    ev[k] = *(const float4*)(w + (size_t)cand[k] * DIM + lane * 4);
    double d = 0.0;
    d = fma(z0, (double)ev[k].x, d);
    d = fma(z1, (double)ev[k].y, d);
    d = fma(z2, (double)ev[k].z, d);
    d = fma(z3, (double)ev[k].w, d);
#pragma unroll
    for (int m = 1; m <= 32; m <<= 1) d += __shfl_xor(d, m, 64);
    sc[k] = np_score(A, (float)d, C32[cand[k]]);
  }
  // np.argmin: min value, first (lowest) index on exact tie
  int win = cand[0], wk = 0;
  float sw = sc[0];
#pragma unroll
  for (int k = 1; k < 6; ++k) {
    const bool take = (sc[k] < sw) || (sc[k] == sw && cand[k] < win);
    sw = take ? sc[k] : sw;
    win = take ? cand[k] : win;
    wk = take ? k : wk;
  }
  const float4 q = ev[wk];
  *(float4*)(out + (size_t)row * DIM + lane * 4) = q;
  double dd = 0.0, tt;
  tt = (double)zv.x - (double)q.x; dd = fma(tt, tt, dd);
  tt = (double)zv.y - (double)q.y; dd = fma(tt, tt, dd);
  tt = (double)zv.z - (double)q.z; dd = fma(tt, tt, dd);
  tt = (double)zv.w - (double)q.w; dd = fma(tt, tt, dd);
#pragma unroll
  for (int m = 1; m <= 32; m <<= 1) dd += __shfl_xor(dd, m, 64);
  if (lane == 0) {
    out[OUT_IDX + row] = (float)win;
    drow[row] = dd;
  }
}

// ---------------- fallback scan (flagged, ~5-50 rows): full f64 np-replica s ----------------
// grid 2048 = 256 code-slices x 8 row-groups; block 256 = 8 rows x 32 codes.
// 32-lane u64-min shuffle reduce -> ONE atomicMin per (row, 32-code slice).
__global__ __launch_bounds__(256) void vq_fb_scan(const float* __restrict__ z,
                                                  const float* __restrict__ w,
                                                  const float* __restrict__ A32,
                                                  const float* __restrict__ C32,
                                                  const int* __restrict__ cnt,
                                                  const int* __restrict__ list,
                                                  u64* __restrict__ mkey) {
  const int slice = blockIdx.x >> 3, rg = blockIdx.x & 7;
  const int cl = threadIdx.x & 31;  // code lane within slice
  const int code = slice * 32 + cl;
  const int rslot = threadIdx.x >> 5;
  const int n = *cnt;
  const float* wr = w + (size_t)code * DIM;
  const float Cc = C32[code];
  for (int r0 = rg * 8; r0 < n; r0 += 64) {
    const int r = r0 + rslot;  // uniform within the 32-lane group
    u64 key = ~0ull;
    int row = 0;
    if (r < n) {
      row = list[r];
      const float* zr = z + (size_t)row * DIM;
      double g0 = 0.0, g1 = 0.0;  // dual accumulators: break f64 fma chain
#pragma unroll 4
      for (int d = 0; d < DIM; d += 4) {
        const float4 zq = *(const float4*)(zr + d);
        const float4 wq = *(const float4*)(wr + d);
        g0 = fma((double)zq.x, (double)wq.x, g0);
        g1 = fma((double)zq.y, (double)wq.y, g1);
        g0 = fma((double)zq.z, (double)wq.z, g0);
        g1 = fma((double)zq.w, (double)wq.w, g1);
      }
      const float s = np_score(A32[row], (float)(g0 + g1), Cc);
      key = ((u64)fmono(s) << 13) | (u64)code;
    }
    // min-reduce across the 32 code-lanes (xor <=16 stays within the group)
#pragma unroll
    for (int m = 1; m <= 16; m <<= 1) {
      const u64 o = __shfl_xor(key, m, 64);
      key = o < key ? o : key;
    }
    if (cl == 0 && r < n) atomicMin(&mkey[row], key);
  }
}

// ---------------- fallback write: winner -> z_q, idx, drow ----------------
__global__ __launch_bounds__(256) void vq_fb_write(const float* __restrict__ z,
                                                   const float* __restrict__ w,
                                                   const int* __restrict__ cnt,
                                                   const int* __restrict__ list,
                                                   const u64* __restrict__ mkey,
                                                   float* __restrict__ out,
                                                   double* __restrict__ drow) {
  const int wv = threadIdx.x >> 6, lane = threadIdx.x & 63;
  const int n = *cnt;
  for (int k = blockIdx.x * 4 + wv; k < n; k += 1024) {
    const int row = list[k];
    const int win = (int)(mkey[row] & 0x1FFFull);
    const float4 zv = *(const float4*)(z + (size_t)row * DIM + lane * 4);
    const float4 q = *(const float4*)(w + (size_t)win * DIM + lane * 4);
    *(float4*)(out + (size_t)row * DIM + lane * 4) = q;
    double dd = 0.0, tt;
    tt = (double)zv.x - (double)q.x; dd = fma(tt, tt, dd);
    tt = (double)zv.y - (double)q.y; dd = fma(tt, tt, dd);
    tt = (double)zv.z - (double)q.z; dd = fma(tt, tt, dd);
    tt = (double)zv.w - (double)q.w; dd = fma(tt, tt, dd);
#pragma unroll
    for (int m = 1; m <= 32; m <<= 1) dd += __shfl_xor(dd, m, 64);
    if (lane == 0) {
      out[OUT_IDX + row] = (float)win;
      drow[row] = dd;
    }
  }
}

// ---------------- loss: deterministic f64 reduction ----------------
__global__ __launch_bounds__(256) void vq_loss(const double* __restrict__ drow,
                                               float* __restrict__ out) {
  __shared__ double sd[256];
  double s = 0.0;
  for (int i = threadIdx.x; i < NROWS; i += 256) s += drow[i];
  sd[threadIdx.x] = s;
  __syncthreads();
  if (threadIdx.x == 0) {
    double tot = 0.0;
    for (int i = 0; i < 256; ++i) tot += sd[i];
    const float loss = (float)(tot / 16777216.0);
    out[OUT_L0] = loss;
    out[OUT_L1] = loss;
  }
}

extern "C" void kernel_launch(void* const* d_in, const int* in_sizes, int n_in,
                              void* d_out, int out_size, void* d_ws, size_t ws_size,
                              hipStream_t stream) {
  const float* z = (const float*)d_in[0];  // f32 [65536, 256]
  const float* w = (const float*)d_in[1];  // f32 [8192, 256]
  float* out = (float*)d_out;
  unsigned char* ws = (unsigned char*)d_ws;
  u16* img = (u16*)(ws + WS_IMG);
  float* hv = (float*)(ws + WS_HV);
  float* C32 = (float*)(ws + WS_C32);
  float* A32 = (float*)(ws + WS_A32);
  int4* t6a = (int4*)(ws + WS_T6A);
  int4* t6b = (int4*)(ws + WS_T6B);
  double* drow = (double*)(ws + WS_DROW);
  int* cnt = (int*)(ws + WS_CNT);
  int* list = (int*)(ws + WS_LIST);
  u64* mkey = (u64*)(ws + WS_MKEY);

  vq_prep<<<NCODES / 4, 256, 0, stream>>>(w, img, hv, cnt);
  vq_rowA<<<NCODES / 4, 256, 0, stream>>>(w, C32);   // np-replica ||e||^2
  vq_rowA<<<NROWS / 4, 256, 0, stream>>>(z, A32);    // np-replica ||z||^2
  vq_main<<<NROWS / 128, 256, 0, stream>>>(z, img, hv, t6a, t6b, cnt, list, mkey);
  vq_refine<<<NROWS / 4, 256, 0, stream>>>(z, w, A32, C32, t6a, t6b, out, drow);
  vq_fb_scan<<<2048, 256, 0, stream>>>(z, w, A32, C32, cnt, list, mkey);
  vq_fb_write<<<256, 256, 0, stream>>>(z, w, cnt, list, mkey, out, drow);
  vq_loss<<<1, 256, 0, stream>>>(drow, out);
}

// Round 14
// 691.421 us; speedup vs baseline: 1.0873x; 1.0169x over previous
//
#include <hip/hip_runtime.h>
#include <stdint.h>

// ---------------- problem constants ----------------
#define NCODES 8192
#define DIM 256
#define NROWS 65536  // 16*64*64

// d_out layout (f32 elements): z_q | codebook_loss | commitment_loss | indices
#define OUT_L0 16777216
#define OUT_L1 16777217
#define OUT_IDX 16777218

// workspace byte offsets
#define WS_IMG 0u        // u16[8192*256] f16 image of w*8192
#define WS_HV 4194304u   // float[8192]   fl32(4096*||e||^2) coarse
#define WS_C32 4227072u  // float[8192]   np-replica f32 ||e||^2
#define WS_A32 4259840u  // float[65536]  np-replica f32 ||z||^2
#define WS_T6A 4521984u  // int4[65536]   (i1,i2,i3, v1<<1|flag)
#define WS_T6B 5570560u  // int4[65536]   (i4,i5,i6, 0)
#define WS_DROW 6619136u // double[65536] per-row exact d^2 of winner
#define WS_CNT 7143424u  // int counter
#define WS_LIST 7143440u // int[65536] flagged rows
#define WS_MKEY 7399696u // u64[65536] atomicMin keys (flagged)

// flag threshold: 0.40 v-units * 512 int-units/v = 204.8 -> 205
#define TAU_INT 205u

typedef __attribute__((ext_vector_type(8))) short s8v;
typedef __attribute__((ext_vector_type(8))) _Float16 f16x8;
typedef __attribute__((ext_vector_type(4))) float f4v;
typedef unsigned short u16;
typedef unsigned long long u64;

__device__ __forceinline__ u16 f2h_bits(float x) {
  return __builtin_bit_cast(u16, (_Float16)x);
}
// monotone f32 -> u32 order map (fb keys; handles either sign)
__device__ __forceinline__ unsigned fmono(float v) {
  unsigned u = __float_as_uint(v);
  return u ^ ((unsigned)((int)u >> 31) | 0x80000000u);
}
// np f32 score: s = fl(fl(A - fl(2*Gf)) + C)  (exact IEEE f32 op sequence)
__device__ __forceinline__ float np_score(float A, float Gf, float C) {
  const float g2 = 2.0f * Gf;
  const float t = A - g2;
  return t + C;
}
// single-instruction median-of-3 (gfx9+): sorted-list insert primitive
__device__ __forceinline__ unsigned med3u(unsigned a, unsigned b, unsigned c) {
  unsigned d;
  asm("v_med3_u32 %0, %1, %2, %3" : "=v"(d) : "v"(a), "v"(b), "v"(c));
  return d;
}

// ---------------- rowA: np-pairwise-replica f32 sum of x_d^2 per row ----------------
__global__ __launch_bounds__(256) void vq_rowA(const float* __restrict__ x,
                                               float* __restrict__ out) {
  __shared__ float sq[4][256];
  __shared__ float rb[4][16];
  const int wv = threadIdx.x >> 6, lane = threadIdx.x & 63;
  const int row = blockIdx.x * 4 + wv;
  const float4 v = *(const float4*)(x + (size_t)row * DIM + lane * 4);
  sq[wv][lane * 4 + 0] = v.x * v.x;
  sq[wv][lane * 4 + 1] = v.y * v.y;
  sq[wv][lane * 4 + 2] = v.z * v.z;
  sq[wv][lane * 4 + 3] = v.w * v.w;
  __syncthreads();
  if (lane < 16) {
    const int j = lane & 7, hb = (lane >> 3) * 128;
    float r = sq[wv][hb + j];
    for (int i = 1; i < 16; ++i) r += sq[wv][hb + i * 8 + j];  // sequential, ascending
    rb[wv][lane] = r;
  }
  __syncthreads();
  if (lane == 0) {
    const float* r = rb[wv];
    const float h0 = ((r[0] + r[1]) + (r[2] + r[3])) + ((r[4] + r[5]) + (r[6] + r[7]));
    const float h1 = ((r[8] + r[9]) + (r[10] + r[11])) + ((r[12] + r[13]) + (r[14] + r[15]));
    out[row] = h0 + h1;
  }
}

// ---------------- prep: f16 image (x8192) + coarse hv + cnt=0 ----------------
__global__ __launch_bounds__(256) void vq_prep(const float* __restrict__ w,
                                               u16* __restrict__ img,
                                               float* __restrict__ hv,
                                               int* __restrict__ cnt) {
  if (blockIdx.x == 0 && threadIdx.x == 0) *cnt = 0;
  const int wv = threadIdx.x >> 6, lane = threadIdx.x & 63;
  const int code = blockIdx.x * 4 + wv;
  const float4 v = *(const float4*)(w + (size_t)code * DIM + lane * 4);
  ushort4 us;
  us.x = f2h_bits(v.x * 8192.0f);
  us.y = f2h_bits(v.y * 8192.0f);
  us.z = f2h_bits(v.z * 8192.0f);
  us.w = f2h_bits(v.w * 8192.0f);
  *(ushort4*)(img + (size_t)code * DIM + lane * 4) = us;
  double s = 0.0;
  s = fma((double)v.x, (double)v.x, s);
  s = fma((double)v.y, (double)v.y, s);
  s = fma((double)v.z, (double)v.z, s);
  s = fma((double)v.w, (double)v.w, s);
#pragma unroll
  for (int m = 1; m <= 32; m <<= 1) s += __shfl_xor(s, m, 64);
  if (lane == 0) hv[code] = (float)(4096.0 * s);
}

// merge two ascending sorted 6-tuples -> smallest 6 of union
// o_k = min over i+j=k of max(a_i, b_j)  (a_0/b_0 = -inf)
#define MERGE6(a1, a2, a3, a4, a5, a6, b1, b2, b3, b4, b5, b6)              \
  {                                                                         \
    const unsigned o1 = min(a1, b1);                                        \
    const unsigned o2 = min(min(a2, b2), max(a1, b1));                      \
    const unsigned o3 = min(min(a3, b3), min(max(a1, b2), max(a2, b1)));    \
    const unsigned o4 =                                                     \
        min(min(a4, b4), min(max(a1, b3), min(max(a2, b2), max(a3, b1))));  \
    const unsigned o5 = min(min(a5, b5), min(min(max(a1, b4), max(a2, b3)), \
                                             min(max(a3, b2), max(a4, b1)))); \
    const unsigned o6 =                                                     \
        min(min(a6, b6), min(min(max(a1, b5), max(a2, b4)),                 \
                             min(max(a3, b3), min(max(a4, b2), max(a5, b1))))); \
    a1 = o1; a2 = o2; a3 = o3; a4 = o4; a5 = o5; a6 = o6;                   \
  }

// ---------------- main: LDS-staged f16 MFMA + per-row top-6 int keys + flag ----------------
// grid 512 x 256 (4 waves). Block owns 128 rows; wave wv owns rows [base+wv*32, +32).
// B staged per 32-code tile (16KB) into 2x16KB LDS dbuf via global_load_lds with
// TRANSPOSED source (r11, 0 bank conflicts). key = (u<<13)|code, u = trunc(512*(v+512)).
// Top-6 keys => flag = (v6-v1 < TAU) certifies np-winner in {i1..i6}.
// launch_bounds(256,2): grid is 2 blocks/CU anyway (512/256); the ,3 bound in r13
// starved the allocator (VGPR_Count 80 < ~140 live) pushing key arrays into AGPRs
// -> accvgpr round-trips around every med3 (455us). 256-VGPR budget keeps keys in VGPR.
__global__ __launch_bounds__(256, 2) void vq_main(const float* __restrict__ z,
                                                  const u16* __restrict__ img,
                                                  const float* __restrict__ hv,
                                                  int4* __restrict__ t6a,
                                                  int4* __restrict__ t6b,
                                                  int* __restrict__ cnt,
                                                  int* __restrict__ list,
                                                  u64* __restrict__ mkey) {
  __shared__ __align__(16) char lds[2][16384];
  const int tid = threadIdx.x, wv = tid >> 6, lane = tid & 63;
  const int ll = lane & 15, lh = lane >> 4;
  const int myrow = blockIdx.x * 128 + wv * 32;  // wave's 32 rows

  // A fragments: lane holds z[myrow+rt*16+ll][c*32 + lh*8 + j] as f16 (64 VGPR)
  f16x8 A[2][8];
#pragma unroll
  for (int rt = 0; rt < 2; ++rt) {
    const float* zr = z + (size_t)(myrow + rt * 16 + ll) * DIM;
#pragma unroll
    for (int c = 0; c < 8; ++c) {
      const float4 a = *(const float4*)(zr + c * 32 + lh * 8);
      const float4 b = *(const float4*)(zr + c * 32 + lh * 8 + 4);
      f16x8 t;
      t[0] = (_Float16)a.x; t[1] = (_Float16)a.y;
      t[2] = (_Float16)a.z; t[3] = (_Float16)a.w;
      t[4] = (_Float16)b.x; t[5] = (_Float16)b.y;
      t[6] = (_Float16)b.z; t[7] = (_Float16)b.w;
      A[rt][c] = t;
    }
  }

  // per-slot (s = rt*4+j) ascending top-6 keys (48 VGPR)
  unsigned k1[8], k2[8], k3[8], k4[8], k5[8], k6[8];
#pragma unroll
  for (int s = 0; s < 8; ++s) {
    k1[s] = 0xFFFFFFFFu; k2[s] = 0xFFFFFFFFu; k3[s] = 0xFFFFFFFFu;
    k4[s] = 0xFFFFFFFFu; k5[s] = 0xFFFFFFFFu; k6[s] = 0xFFFFFFFFu;
  }

  // transposed staging source offsets (r11): dest linear, src = code*512 + g*16
  unsigned soff[4];
#pragma unroll
  for (int p = 0; p < 4; ++p)
    soff[p] = (unsigned)((lane & 31) * 512 + ((p * 4 + wv) * 2 + (lane >> 5)) * 16);

  auto STAGE = [&](int t, int buf) {
    const char* src = (const char*)img + (size_t)t * 16384;
#pragma unroll
    for (int p = 0; p < 4; ++p) {
      __builtin_amdgcn_global_load_lds(
          (const __attribute__((address_space(1))) unsigned int*)(src + soff[p]),
          (__attribute__((address_space(3))) unsigned int*)(&lds[buf][(p * 4 + wv) * 1024]),
          16, 0, 0);
    }
  };

  // per-lane ds_read base: lh*512 + ll*16; c,ct offsets are immediates
  const int rbase = lh * 512 + ll * 16;

  STAGE(0, 0);
  __syncthreads();
#pragma unroll 1
  for (int t = 0; t < 256; ++t) {
    const int buf = t & 1;
    if (t + 1 < 256) STAGE(t + 1, buf ^ 1);  // prefetch flies under compute

    const float hb0 = fmaf(hv[t * 32 + ll], 512.0f, 262144.0f);       // (hv+512)*512
    const float hb1 = fmaf(hv[t * 32 + 16 + ll], 512.0f, 262144.0f);
    const char* bp = &lds[buf][rbase];

    f4v a00 = (f4v){0.f, 0.f, 0.f, 0.f}, a01 = (f4v){0.f, 0.f, 0.f, 0.f};
    f4v a10 = (f4v){0.f, 0.f, 0.f, 0.f}, a11 = (f4v){0.f, 0.f, 0.f, 0.f};
#pragma unroll
    for (int c = 0; c < 8; ++c) {
      const f16x8 b0 = *(const f16x8*)(bp + c * 2048);        // ct=0
      const f16x8 b1 = *(const f16x8*)(bp + c * 2048 + 256);  // ct=1
      a00 = __builtin_amdgcn_mfma_f32_16x16x32_f16(A[0][c], b0, a00, 0, 0, 0);
      a01 = __builtin_amdgcn_mfma_f32_16x16x32_f16(A[0][c], b1, a01, 0, 0, 0);
      a10 = __builtin_amdgcn_mfma_f32_16x16x32_f16(A[1][c], b0, a10, 0, 0, 0);
      a11 = __builtin_amdgcn_mfma_f32_16x16x32_f16(A[1][c], b1, a11, 0, 0, 0);
    }

    const unsigned iv0 = (unsigned)(t * 32 + ll);
    const unsigned iv1 = iv0 + 16u;
#pragma unroll
    for (int rt = 0; rt < 2; ++rt) {
      const f4v& c0 = rt ? a10 : a00;
      const f4v& c1 = rt ? a11 : a01;
#pragma unroll
      for (int j = 0; j < 4; ++j) {
        const int s = rt * 4 + j;
        const float u0 = fmaf(c0[j], -512.0f, hb0);
        const unsigned key0 = (((unsigned)u0) << 13) | iv0;
        const unsigned n1 = min(k1[s], key0);
        const unsigned n2 = med3u(k1[s], key0, k2[s]);
        const unsigned n3 = med3u(k2[s], key0, k3[s]);
        const unsigned n4 = med3u(k3[s], key0, k4[s]);
        const unsigned n5 = med3u(k4[s], key0, k5[s]);
        const unsigned n6 = med3u(k5[s], key0, k6[s]);
        const float u1 = fmaf(c1[j], -512.0f, hb1);
        const unsigned key1 = (((unsigned)u1) << 13) | iv1;
        k1[s] = min(n1, key1);
        k2[s] = med3u(n1, key1, n2);
        k3[s] = med3u(n2, key1, n3);
        k4[s] = med3u(n3, key1, n4);
        k5[s] = med3u(n4, key1, n5);
        k6[s] = med3u(n5, key1, n6);
      }
    }
    __syncthreads();  // drains prefetch vmcnt + all waves done with buf
  }

  // ---- merge across the 16 column-lanes (butterfly); wave owns its 32 rows ----
#pragma unroll
  for (int rt = 0; rt < 2; ++rt)
#pragma unroll
    for (int j = 0; j < 4; ++j) {
      const int s = rt * 4 + j;
      unsigned a1 = k1[s], a2 = k2[s], a3 = k3[s], a4 = k4[s], a5 = k5[s], a6 = k6[s];
#pragma unroll
      for (int m = 1; m <= 8; m <<= 1) {
        unsigned b1 = (unsigned)__shfl_xor((int)a1, m, 64);
        unsigned b2 = (unsigned)__shfl_xor((int)a2, m, 64);
        unsigned b3 = (unsigned)__shfl_xor((int)a3, m, 64);
        unsigned b4 = (unsigned)__shfl_xor((int)a4, m, 64);
        unsigned b5 = (unsigned)__shfl_xor((int)a5, m, 64);
        unsigned b6 = (unsigned)__shfl_xor((int)a6, m, 64);
        MERGE6(a1, a2, a3, a4, a5, a6, b1, b2, b3, b4, b5, b6);
      }
      if (ll == 0) {  // C/D: col=lane&15, row=(lane>>4)*4+j
        const int row = myrow + rt * 16 + lh * 4 + j;
        const int flag = ((a6 >> 13) - (a1 >> 13)) < TAU_INT ? 1 : 0;
        t6a[row] = make_int4((int)(a1 & 0x1FFFu), (int)(a2 & 0x1FFFu), (int)(a3 & 0x1FFFu),
                             (int)(((a1 >> 13) << 1) | (unsigned)flag));
        t6b[row] = make_int4((int)(a4 & 0x1FFFu), (int)(a5 & 0x1FFFu), (int)(a6 & 0x1FFFu), 0);
        if (flag) {
          mkey[row] = ~0ull;
          list[atomicAdd(cnt, 1)] = row;
        }
      }
    }
}

// ---------------- refine (unflagged): np-replica s over top-6, first-index tie ----------------
__global__ __launch_bounds__(256) void vq_refine(const float* __restrict__ z,
                                                 const float* __restrict__ w,
                                                 const float* __restrict__ A32,
                                                 const float* __restrict__ C32,
                                                 const int4* __restrict__ t6a,
                                                 const int4* __restrict__ t6b,
                                                 float* __restrict__ out,
                                                 double* __restrict__ drow) {
  const int wv = threadIdx.x >> 6, lane = threadIdx.x & 63;
  const int row = blockIdx.x * 4 + wv;
  const int4 ca = t6a[row];
  if (ca.w & 1) return;  // flagged -> fallback path owns this row
  const int4 cb = t6b[row];
  const float4 zv = *(const float4*)(z + (size_t)row * DIM + lane * 4);
  const double z0 = (double)zv.x, z1 = (double)zv.y, z2 = (double)zv.z, z3 = (double)zv.w;
  const int cand[6] = {ca.x, ca.y, ca.z, cb.x, cb.y, cb.z};
  float4 ev[6];
  float sc[6];
  const float A = A32[row];
#pragma unroll
  for (int k = 0; k < 6; ++k) {
    ev[k] = *(const float4*)(w + (size_t)cand[k] * DIM + lane * 4);
    double d = 0.0;
    d = fma(z0, (double)ev[k].x, d);
    d = fma(z1, (double)ev[k].y, d);
    d = fma(z2, (double)ev[k].z, d);
    d = fma(z3, (double)ev[k].w, d);
#pragma unroll
    for (int m = 1; m <= 32; m <<= 1) d += __shfl_xor(d, m, 64);
    sc[k] = np_score(A, (float)d, C32[cand[k]]);
  }
  // np.argmin: min value, first (lowest) index on exact tie
  int win = cand[0], wk = 0;
  float sw = sc[0];
#pragma unroll
  for (int k = 1; k < 6; ++k) {
    const bool take = (sc[k] < sw) || (sc[k] == sw && cand[k] < win);
    sw = take ? sc[k] : sw;
    win = take ? cand[k] : win;
    wk = take ? k : wk;
  }
  const float4 q = ev[wk];
  *(float4*)(out + (size_t)row * DIM + lane * 4) = q;
  double dd = 0.0, tt;
  tt = (double)zv.x - (double)q.x; dd = fma(tt, tt, dd);
  tt = (double)zv.y - (double)q.y; dd = fma(tt, tt, dd);
  tt = (double)zv.z - (double)q.z; dd = fma(tt, tt, dd);
  tt = (double)zv.w - (double)q.w; dd = fma(tt, tt, dd);
#pragma unroll
  for (int m = 1; m <= 32; m <<= 1) dd += __shfl_xor(dd, m, 64);
  if (lane == 0) {
    out[OUT_IDX + row] = (float)win;
    drow[row] = dd;
  }
}

// ---------------- fallback scan (flagged, ~5-50 rows): full f64 np-replica s ----------------
// grid 2048 = 256 code-slices x 8 row-groups; block 256 = 8 rows x 32 codes.
// 32-lane u64-min shuffle reduce -> ONE atomicMin per (row, 32-code slice).
__global__ __launch_bounds__(256) void vq_fb_scan(const float* __restrict__ z,
                                                  const float* __restrict__ w,
                                                  const float* __restrict__ A32,
                                                  const float* __restrict__ C32,
                                                  const int* __restrict__ cnt,
                                                  const int* __restrict__ list,
                                                  u64* __restrict__ mkey) {
  const int slice = blockIdx.x >> 3, rg = blockIdx.x & 7;
  const int cl = threadIdx.x & 31;  // code lane within slice
  const int code = slice * 32 + cl;
  const int rslot = threadIdx.x >> 5;
  const int n = *cnt;
  const float* wr = w + (size_t)code * DIM;
  const float Cc = C32[code];
  for (int r0 = rg * 8; r0 < n; r0 += 64) {
    const int r = r0 + rslot;  // uniform within the 32-lane group
    u64 key = ~0ull;
    int row = 0;
    if (r < n) {
      row = list[r];
      const float* zr = z + (size_t)row * DIM;
      double g0 = 0.0, g1 = 0.0;  // dual accumulators: break f64 fma chain
#pragma unroll 4
      for (int d = 0; d < DIM; d += 4) {
        const float4 zq = *(const float4*)(zr + d);
        const float4 wq = *(const float4*)(wr + d);
        g0 = fma((double)zq.x, (double)wq.x, g0);
        g1 = fma((double)zq.y, (double)wq.y, g1);
        g0 = fma((double)zq.z, (double)wq.z, g0);
        g1 = fma((double)zq.w, (double)wq.w, g1);
      }
      const float s = np_score(A32[row], (float)(g0 + g1), Cc);
      key = ((u64)fmono(s) << 13) | (u64)code;
    }
    // min-reduce across the 32 code-lanes (xor <=16 stays within the group)
#pragma unroll
    for (int m = 1; m <= 16; m <<= 1) {
      const u64 o = __shfl_xor(key, m, 64);
      key = o < key ? o : key;
    }
    if (cl == 0 && r < n) atomicMin(&mkey[row], key);
  }
}

// ---------------- fallback write: winner -> z_q, idx, drow ----------------
__global__ __launch_bounds__(256) void vq_fb_write(const float* __restrict__ z,
                                                   const float* __restrict__ w,
                                                   const int* __restrict__ cnt,
                                                   const int* __restrict__ list,
                                                   const u64* __restrict__ mkey,
                                                   float* __restrict__ out,
                                                   double* __restrict__ drow) {
  const int wv = threadIdx.x >> 6, lane = threadIdx.x & 63;
  const int n = *cnt;
  for (int k = blockIdx.x * 4 + wv; k < n; k += 1024) {
    const int row = list[k];
    const int win = (int)(mkey[row] & 0x1FFFull);
    const float4 zv = *(const float4*)(z + (size_t)row * DIM + lane * 4);
    const float4 q = *(const float4*)(w + (size_t)win * DIM + lane * 4);
    *(float4*)(out + (size_t)row * DIM + lane * 4) = q;
    double dd = 0.0, tt;
    tt = (double)zv.x - (double)q.x; dd = fma(tt, tt, dd);
    tt = (double)zv.y - (double)q.y; dd = fma(tt, tt, dd);
    tt = (double)zv.z - (double)q.z; dd = fma(tt, tt, dd);
    tt = (double)zv.w - (double)q.w; dd = fma(tt, tt, dd);
#pragma unroll
    for (int m = 1; m <= 32; m <<= 1) dd += __shfl_xor(dd, m, 64);
    if (lane == 0) {
      out[OUT_IDX + row] = (float)win;
      drow[row] = dd;
    }
  }
}

// ---------------- loss: deterministic f64 reduction ----------------
__global__ __launch_bounds__(256) void vq_loss(const double* __restrict__ drow,
                                               float* __restrict__ out) {
  __shared__ double sd[256];
  double s = 0.0;
  for (int i = threadIdx.x; i < NROWS; i += 256) s += drow[i];
  sd[threadIdx.x] = s;
  __syncthreads();
  if (threadIdx.x == 0) {
    double tot = 0.0;
    for (int i = 0; i < 256; ++i) tot += sd[i];
    const float loss = (float)(tot / 16777216.0);
    out[OUT_L0] = loss;
    out[OUT_L1] = loss;
  }
}

extern "C" void kernel_launch(void* const* d_in, const int* in_sizes, int n_in,
                              void* d_out, int out_size, void* d_ws, size_t ws_size,
                              hipStream_t stream) {
  const float* z = (const float*)d_in[0];  // f32 [65536, 256]
  const float* w = (const float*)d_in[1];  // f32 [8192, 256]
  float* out = (float*)d_out;
  unsigned char* ws = (unsigned char*)d_ws;
  u16* img = (u16*)(ws + WS_IMG);
  float* hv = (float*)(ws + WS_HV);
  float* C32 = (float*)(ws + WS_C32);
  float* A32 = (float*)(ws + WS_A32);
  int4* t6a = (int4*)(ws + WS_T6A);
  int4* t6b = (int4*)(ws + WS_T6B);
  double* drow = (double*)(ws + WS_DROW);
  int* cnt = (int*)(ws + WS_CNT);
  int* list = (int*)(ws + WS_LIST);
  u64* mkey = (u64*)(ws + WS_MKEY);

  vq_prep<<<NCODES / 4, 256, 0, stream>>>(w, img, hv, cnt);
  vq_rowA<<<NCODES / 4, 256, 0, stream>>>(w, C32);   // np-replica ||e||^2
  vq_rowA<<<NROWS / 4, 256, 0, stream>>>(z, A32);    // np-replica ||z||^2
  vq_main<<<NROWS / 128, 256, 0, stream>>>(z, img, hv, t6a, t6b, cnt, list, mkey);
  vq_refine<<<NROWS / 4, 256, 0, stream>>>(z, w, A32, C32, t6a, t6b, out, drow);
  vq_fb_scan<<<2048, 256, 0, stream>>>(z, w, A32, C32, cnt, list, mkey);
  vq_fb_write<<<256, 256, 0, stream>>>(z, w, cnt, list, mkey, out, drow);
  vq_loss<<<1, 256, 0, stream>>>(drow, out);
}